// Round 1
// baseline (840.006 us; speedup 1.0000x reference)
//
#include <hip/hip_runtime.h>
#include <math.h>

constexpr float NEG_SLOPE = 0.2f;
constexpr float BN_EPS_C = 1e-5f;

// ---------------- CSR build ----------------

__global__ void count_kernel(const int* __restrict__ ei, int* __restrict__ counts,
                             int E, int N) {
    int i = blockIdx.x * blockDim.x + threadIdx.x;
    int ET = E + N;
    if (i >= ET) return;
    int d = (i < E) ? ei[E + i] : (i - E);
    atomicAdd(&counts[d], 1);
}

__global__ void scan_kernel(const int* __restrict__ counts, int* __restrict__ row_ptr, int n) {
    __shared__ int partial[1024];
    int t = threadIdx.x;
    int CH = (n + 1023) >> 10;
    int beg = t * CH;
    int end = min(beg + CH, n);
    int s = 0;
    for (int i = beg; i < end; ++i) s += counts[i];
    partial[t] = s;
    __syncthreads();
    for (int off = 1; off < 1024; off <<= 1) {
        int v = (t >= off) ? partial[t - off] : 0;
        __syncthreads();
        partial[t] += v;
        __syncthreads();
    }
    int prefix = (t == 0) ? 0 : partial[t - 1];
    for (int i = beg; i < end; ++i) {
        row_ptr[i] = prefix;
        prefix += counts[i];
    }
    if (t == 1023) row_ptr[n] = prefix;
}

__global__ void scatter_kernel(const int* __restrict__ ei, const int* __restrict__ row_ptr,
                               int* __restrict__ cursor, int* __restrict__ srcs, int E, int N) {
    int i = blockIdx.x * blockDim.x + threadIdx.x;
    int ET = E + N;
    if (i >= ET) return;
    int s, d;
    if (i < E) { s = ei[i]; d = ei[E + i]; }
    else       { s = i - E; d = s; }
    int pos = row_ptr[d] + atomicAdd(&cursor[d], 1);
    srcs[pos] = s;
}

// ---------------- fused GEMM (h = X @ W^T) + attention alphas ----------------
// X: [N,128], W: [FOUT,128], a_src/a_dst flat [FOUT] (since j = head*16+c maps flatly)
// outputs: h [N,FOUT], asrc/adst [N,H]

template<int FOUT, int H>
__global__ __launch_bounds__(256)
void gemm_alpha_kernel(const float* __restrict__ X, const float* __restrict__ W,
                       const float* __restrict__ a_src, const float* __restrict__ a_dst,
                       float* __restrict__ h, float* __restrict__ asrc, float* __restrict__ adst,
                       int N) {
    constexpr int NJ = (FOUT + 15) / 16;
    constexpr int JP = NJ * 16;
    __shared__ float Xs[64][132];
    __shared__ float Ws[JP][132];
    const int t = threadIdx.x;
    const int n0 = blockIdx.x * 64;

    // stage X tile (64 rows x 128) coalesced
#pragma unroll
    for (int i = 0; i < 8; ++i) {
        int lin = t + i * 256;          // float4 units
        int r = lin >> 5;
        int k4 = (lin & 31) << 2;
        int gn = n0 + r;
        float4 v = make_float4(0.f, 0.f, 0.f, 0.f);
        if (gn < N) v = *reinterpret_cast<const float4*>(&X[(size_t)gn * 128 + k4]);
        *reinterpret_cast<float4*>(&Xs[r][k4]) = v;
    }
    // stage W (FOUT x 128), zero-pad rows >= FOUT
    constexpr int WITERS = (JP * 32 + 255) / 256;
#pragma unroll
    for (int i = 0; i < WITERS; ++i) {
        int lin = t + i * 256;
        if (lin < JP * 32) {
            int j = lin >> 5;
            int k4 = (lin & 31) << 2;
            float4 v = make_float4(0.f, 0.f, 0.f, 0.f);
            if (j < FOUT) v = *reinterpret_cast<const float4*>(&W[(size_t)j * 128 + k4]);
            *reinterpret_cast<float4*>(&Ws[j][k4]) = v;
        }
    }
    __syncthreads();

    const int tr = t >> 4;   // 16 row-groups of 4 nodes
    const int tc = t & 15;   // 16 col threads; thread covers j = tc + jj*16
    float acc[4][NJ];
#pragma unroll
    for (int i = 0; i < 4; ++i)
#pragma unroll
        for (int jj = 0; jj < NJ; ++jj) acc[i][jj] = 0.f;

    for (int k = 0; k < 128; k += 4) {
        float4 xv[4];
#pragma unroll
        for (int i = 0; i < 4; ++i)
            xv[i] = *reinterpret_cast<const float4*>(&Xs[tr * 4 + i][k]);
        float4 wv[NJ];
#pragma unroll
        for (int jj = 0; jj < NJ; ++jj)
            wv[jj] = *reinterpret_cast<const float4*>(&Ws[tc + jj * 16][k]);
#pragma unroll
        for (int i = 0; i < 4; ++i)
#pragma unroll
            for (int jj = 0; jj < NJ; ++jj) {
                acc[i][jj] += xv[i].x * wv[jj].x;
                acc[i][jj] += xv[i].y * wv[jj].y;
                acc[i][jj] += xv[i].z * wv[jj].z;
                acc[i][jj] += xv[i].w * wv[jj].w;
            }
    }

#pragma unroll
    for (int i = 0; i < 4; ++i) {
        int gn = n0 + tr * 4 + i;
        bool ok = gn < N;
        float ps = 0.f, pd = 0.f;
#pragma unroll
        for (int jj = 0; jj < NJ; ++jj) {
            int j = tc + jj * 16;
            float v = acc[i][jj];
            bool jok = (j < FOUT);
            if (ok && jok) h[(size_t)gn * FOUT + j] = v;
            float av = jok ? a_src[j] : 0.f;
            float bv = jok ? a_dst[j] : 0.f;
            if constexpr (H == 8) {
                // head jj, channel tc: reduce over the 16 channel-lanes
                float p = v * av;
                float q = v * bv;
#pragma unroll
                for (int off = 1; off < 16; off <<= 1) {
                    p += __shfl_xor(p, off, 16);
                    q += __shfl_xor(q, off, 16);
                }
                if (tc == 0 && ok) {
                    asrc[(size_t)gn * 8 + jj] = p;
                    adst[(size_t)gn * 8 + jj] = q;
                }
            } else {
                ps += v * av;
                pd += v * bv;
            }
        }
        if constexpr (H == 1) {
#pragma unroll
            for (int off = 1; off < 16; off <<= 1) {
                ps += __shfl_xor(ps, off, 16);
                pd += __shfl_xor(pd, off, 16);
            }
            if (tc == 0 && ok) { asrc[gn] = ps; adst[gn] = pd; }
        }
    }
}

// ---------------- segment max + sum (softmax stats) ----------------

template<int H>
__global__ void maxsum_kernel(const int* __restrict__ row_ptr, const int* __restrict__ srcs,
                              const float* __restrict__ asrc, const float* __restrict__ adst,
                              float* __restrict__ emax, float* __restrict__ invden, int N) {
    int t = blockIdx.x * blockDim.x + threadIdx.x;
    int node = t / H;
    int hd = t - node * H;
    if (node >= N) return;
    int beg = row_ptr[node], end = row_ptr[node + 1];
    float ad = adst[(size_t)node * H + hd];
    float m = -1e30f;
    for (int j = beg; j < end; ++j) {
        int s = srcs[j];
        float e = asrc[(size_t)s * H + hd] + ad;
        e = (e > 0.f) ? e : NEG_SLOPE * e;
        m = fmaxf(m, e);
    }
    float sum = 0.f;
    for (int j = beg; j < end; ++j) {
        int s = srcs[j];
        float e = asrc[(size_t)s * H + hd] + ad;
        e = (e > 0.f) ? e : NEG_SLOPE * e;
        sum += __expf(e - m);
    }
    emax[(size_t)node * H + hd] = m;
    invden[(size_t)node * H + hd] = 1.0f / (sum + 1e-16f);
}

// ---------------- message aggregation, F=128, H=8, fused bias+BN+ELU ----------------

__global__ __launch_bounds__(256)
void message128_kernel(const float* __restrict__ h, const int* __restrict__ row_ptr,
                       const int* __restrict__ srcs,
                       const float* __restrict__ asrc, const float* __restrict__ adst,
                       const float* __restrict__ emax, const float* __restrict__ invden,
                       const float* __restrict__ bias,
                       const float* __restrict__ bn_g, const float* __restrict__ bn_b,
                       const float* __restrict__ bn_m, const float* __restrict__ bn_v,
                       float* __restrict__ out, int N) {
    int node = blockIdx.x * 2 + (threadIdx.x >> 7);
    if (node >= N) return;
    int c = threadIdx.x & 127;
    int hd = c >> 4;
    int beg = row_ptr[node], end = row_ptr[node + 1];
    float ad = adst[(size_t)node * 8 + hd];
    float mx = emax[(size_t)node * 8 + hd];
    float inv = invden[(size_t)node * 8 + hd];
    float acc = 0.f;
    for (int j = beg; j < end; ++j) {
        int s = srcs[j];
        float e = asrc[(size_t)s * 8 + hd] + ad;
        e = (e > 0.f) ? e : NEG_SLOPE * e;
        float w = __expf(e - mx) * inv;
        acc += h[(size_t)s * 128 + c] * w;
    }
    float v = acc + bias[c];
    v = (v - bn_m[c]) * rsqrtf(bn_v[c] + BN_EPS_C) * bn_g[c] + bn_b[c];
    v = (v > 0.f) ? v : expm1f(v);
    out[(size_t)node * 128 + c] = v;
}

// ---------------- message aggregation, F=40, H=1, bias only, writes d_out ----------------

__global__ __launch_bounds__(256)
void message40_kernel(const float* __restrict__ h2, const int* __restrict__ row_ptr,
                      const int* __restrict__ srcs,
                      const float* __restrict__ asrc, const float* __restrict__ adst,
                      const float* __restrict__ emax, const float* __restrict__ invden,
                      const float* __restrict__ b2, float* __restrict__ out, int N) {
    int node = blockIdx.x * 4 + (threadIdx.x >> 6);
    if (node >= N) return;
    int c = threadIdx.x & 63;
    int beg = row_ptr[node], end = row_ptr[node + 1];
    float ad = adst[node];
    float mx = emax[node];
    float inv = invden[node];
    float acc = 0.f;
    for (int j = beg; j < end; ++j) {
        int s = srcs[j];
        float e = asrc[s] + ad;
        e = (e > 0.f) ? e : NEG_SLOPE * e;
        float w = __expf(e - mx) * inv;
        if (c < 40) acc += h2[(size_t)s * 40 + c] * w;
    }
    if (c < 40) out[(size_t)node * 40 + c] = acc + b2[c];
}

// ---------------- launcher ----------------

extern "C" void kernel_launch(void* const* d_in, const int* in_sizes, int n_in,
                              void* d_out, int out_size, void* d_ws, size_t ws_size,
                              hipStream_t stream) {
    const float* x   = (const float*)d_in[0];
    const int*   ei  = (const int*)d_in[1];
    const float* W0  = (const float*)d_in[2];
    const float* as0 = (const float*)d_in[3];
    const float* ad0 = (const float*)d_in[4];
    const float* b0  = (const float*)d_in[5];
    const float* g0  = (const float*)d_in[6];
    const float* bb0 = (const float*)d_in[7];
    const float* m0  = (const float*)d_in[8];
    const float* v0  = (const float*)d_in[9];
    const float* W1  = (const float*)d_in[10];
    const float* as1 = (const float*)d_in[11];
    const float* ad1 = (const float*)d_in[12];
    const float* b1  = (const float*)d_in[13];
    const float* g1  = (const float*)d_in[14];
    const float* bb1 = (const float*)d_in[15];
    const float* m1  = (const float*)d_in[16];
    const float* v1  = (const float*)d_in[17];
    const float* W2  = (const float*)d_in[18];
    const float* as2 = (const float*)d_in[19];
    const float* ad2 = (const float*)d_in[20];
    const float* b2  = (const float*)d_in[21];

    const int N  = in_sizes[0] / 128;
    const int E  = in_sizes[1] / 2;
    const int ET = E + N;

    char* wsp = (char*)d_ws;
    int* row_ptr = (int*)wsp;   wsp += (size_t)(N + 1) * 4;
    int* cursor  = (int*)wsp;   wsp += (size_t)N * 4;
    int* srcs    = (int*)wsp;   wsp += (size_t)ET * 4;
    float* h     = (float*)wsp; wsp += (size_t)N * 128 * 4;
    float* feat  = (float*)wsp; wsp += (size_t)N * 128 * 4;
    float* asr   = (float*)wsp; wsp += (size_t)N * 8 * 4;
    float* adt   = (float*)wsp; wsp += (size_t)N * 8 * 4;
    float* emax  = (float*)wsp; wsp += (size_t)N * 8 * 4;
    float* invd  = (float*)wsp; wsp += (size_t)N * 8 * 4;

    // CSR build (once, reused by all 3 layers)
    hipMemsetAsync(cursor, 0, (size_t)N * 4, stream);
    count_kernel<<<(ET + 255) / 256, 256, 0, stream>>>(ei, cursor, E, N);
    scan_kernel<<<1, 1024, 0, stream>>>(cursor, row_ptr, N);
    hipMemsetAsync(cursor, 0, (size_t)N * 4, stream);
    scatter_kernel<<<(ET + 255) / 256, 256, 0, stream>>>(ei, row_ptr, cursor, srcs, E, N);

    const int gemm_grid = (N + 63) / 64;

    // layer 0: x -> feat
    gemm_alpha_kernel<128, 8><<<gemm_grid, 256, 0, stream>>>(x, W0, as0, ad0, h, asr, adt, N);
    maxsum_kernel<8><<<(N * 8 + 255) / 256, 256, 0, stream>>>(row_ptr, srcs, asr, adt, emax, invd, N);
    message128_kernel<<<(N + 1) / 2, 256, 0, stream>>>(h, row_ptr, srcs, asr, adt, emax, invd,
                                                       b0, g0, bb0, m0, v0, feat, N);
    // layer 1: feat -> feat (reads h, safe in-place)
    gemm_alpha_kernel<128, 8><<<gemm_grid, 256, 0, stream>>>(feat, W1, as1, ad1, h, asr, adt, N);
    maxsum_kernel<8><<<(N * 8 + 255) / 256, 256, 0, stream>>>(row_ptr, srcs, asr, adt, emax, invd, N);
    message128_kernel<<<(N + 1) / 2, 256, 0, stream>>>(h, row_ptr, srcs, asr, adt, emax, invd,
                                                       b1, g1, bb1, m1, v1, feat, N);
    // layer 2: feat -> d_out
    gemm_alpha_kernel<40, 1><<<gemm_grid, 256, 0, stream>>>(feat, W2, as2, ad2, h, asr, adt, N);
    maxsum_kernel<1><<<(N + 255) / 256, 256, 0, stream>>>(row_ptr, srcs, asr, adt, emax, invd, N);
    message40_kernel<<<(N + 3) / 4, 256, 0, stream>>>(h, row_ptr, srcs, asr, adt, emax, invd,
                                                      b2, (float*)d_out, N);
}